// Round 5
// baseline (675.314 us; speedup 1.0000x reference)
//
#include <hip/hip_runtime.h>

#define N_INPUT 256
#define HS 32
#define SCAN_T 1024

typedef __attribute__((ext_vector_type(8))) short bf16x8;
typedef __attribute__((ext_vector_type(4))) float f32x4;

// fp32 -> bf16 bits, round-to-nearest-even
__device__ __forceinline__ unsigned short f2bf(float f) {
    unsigned u = __float_as_uint(f);
    unsigned r = u + 0x7FFFu + ((u >> 16) & 1u);
    return (unsigned short)(r >> 16);
}

// ---------------- CSR build: counting sort of edges by src ----------------

__global__ void zero_deg_kernel(int* __restrict__ deg, int N) {
    int i = blockIdx.x * blockDim.x + threadIdx.x;
    if (i < N) deg[i] = 0;
}

__global__ void hist_kernel(const int* __restrict__ src, int* __restrict__ deg, int E) {
    int e = blockIdx.x * blockDim.x + threadIdx.x;
    if (e < E) atomicAdd(deg + src[e], 1);
}

// single-block exclusive scan of deg[0..N) -> rowstart[0..N], copy to cursor.
// 1024 threads x ~98 serial elems + Hillis-Steele over partials. ~micro-scale.
__global__ __launch_bounds__(SCAN_T) void scan_kernel(
        const int* __restrict__ deg, int* __restrict__ rowstart,
        int* __restrict__ cursor, int N, int E) {
    __shared__ int sums[SCAN_T];
    int t = threadIdx.x;
    int chunk = (N + SCAN_T - 1) / SCAN_T;
    int lo = t * chunk, hi = min(lo + chunk, N);
    int s = 0;
    for (int i = lo; i < hi; ++i) s += deg[i];
    sums[t] = s;
    __syncthreads();
    for (int off = 1; off < SCAN_T; off <<= 1) {
        int v = (t >= off) ? sums[t - off] : 0;
        __syncthreads();
        sums[t] += v;
        __syncthreads();
    }
    int prefix = (t > 0) ? sums[t - 1] : 0;  // exclusive
    for (int i = lo; i < hi; ++i) {
        rowstart[i] = prefix;
        cursor[i] = prefix;
        prefix += deg[i];
    }
    if (t == SCAN_T - 1) rowstart[N] = E;
}

__global__ void scatter_kernel(const int* __restrict__ src, const int* __restrict__ dst,
                               int* __restrict__ cursor, int* __restrict__ sorted_dst, int E) {
    int e = blockIdx.x * blockDim.x + threadIdx.x;
    if (e < E) {
        int pos = atomicAdd(cursor + src[e], 1);
        sorted_dst[pos] = dst[e];
    }
}

// ---------------- Fused Q/K/V projection (MFMA, unchanged from R4) ----------------
__global__ __launch_bounds__(256) void qkv_mfma_kernel(
        const float* __restrict__ X, const float* __restrict__ Wq,
        const float* __restrict__ Wk, const float* __restrict__ Wv,
        float* __restrict__ Q, float* __restrict__ K, float* __restrict__ V, int N) {
    __shared__ unsigned short sB[6 * 8 * 64 * 8];  // 48 KB, frag-ordered bf16 W

    int tid = threadIdx.x;
    for (int i = 0; i < 12; ++i) {
        int c = tid + i * 256;
        int s = c >> 9;
        int t = (c >> 6) & 7;
        int L = c & 63;
        const float* wm = (s < 2) ? Wq : (s < 4) ? Wk : Wv;
        const float* wsrc = wm + (size_t)(t * 32 + (L >> 4) * 8) * HS + (s & 1) * 16 + (L & 15);
        unsigned e0 = f2bf(wsrc[0 * HS]) | ((unsigned)f2bf(wsrc[1 * HS]) << 16);
        unsigned e1 = f2bf(wsrc[2 * HS]) | ((unsigned)f2bf(wsrc[3 * HS]) << 16);
        unsigned e2 = f2bf(wsrc[4 * HS]) | ((unsigned)f2bf(wsrc[5 * HS]) << 16);
        unsigned e3 = f2bf(wsrc[6 * HS]) | ((unsigned)f2bf(wsrc[7 * HS]) << 16);
        ((uint4*)sB)[c] = make_uint4(e0, e1, e2, e3);
    }
    __syncthreads();

    int wave = tid >> 6;
    int L = tid & 63;
    int quad = L >> 4;
    int lane16 = L & 15;
    int mt = blockIdx.x * 4 + wave;
    if (mt * 16 >= N) return;  // no barriers past this point

    const float* xrow = X + (size_t)(mt * 16 + lane16) * N_INPUT + quad * 8;
    bf16x8 afrag[8];
#pragma unroll
    for (int t = 0; t < 8; ++t) {
        float4 a0 = *(const float4*)(xrow + t * 32);
        float4 a1 = *(const float4*)(xrow + t * 32 + 4);
        bf16x8 f;
        f[0] = (short)f2bf(a0.x); f[1] = (short)f2bf(a0.y);
        f[2] = (short)f2bf(a0.z); f[3] = (short)f2bf(a0.w);
        f[4] = (short)f2bf(a1.x); f[5] = (short)f2bf(a1.y);
        f[6] = (short)f2bf(a1.z); f[7] = (short)f2bf(a1.w);
        afrag[t] = f;
    }

#pragma unroll
    for (int s = 0; s < 6; ++s) {
        f32x4 acc = {0.f, 0.f, 0.f, 0.f};
#pragma unroll
        for (int t = 0; t < 8; ++t) {
            bf16x8 bfrag = *((const bf16x8*)sB + (s * 8 + t) * 64 + L);
            acc = __builtin_amdgcn_mfma_f32_16x16x32_bf16(afrag[t], bfrag, acc, 0, 0, 0);
        }
        float* om = (s < 2) ? Q : (s < 4) ? K : V;
        int col = (s & 1) * 16 + lane16;
#pragma unroll
        for (int r = 0; r < 4; ++r) {
            int row = mt * 16 + quad * 4 + r;
            om[(size_t)row * HS + col] = acc[r];
        }
    }
}

// ---------------- Fused per-node edge pass: score+exp+denom+aggregate ----------------
// One 32-lane group per node walks its CSR segment. No max pass (scores bounded,
// alpha ratio identical). acc/den live in registers; ONE coalesced store per node.
// Replaces score_kernel+agg_kernel (2x168 us: 200 MB atomic write-through at L3,
// double edge-list read, per-edge Q re-gather).
__global__ __launch_bounds__(256) void fused_agg_kernel(
        const int* __restrict__ rowstart, const int* __restrict__ sorted_dst,
        const float* __restrict__ Q, const float* __restrict__ K,
        const float* __restrict__ V, float* __restrict__ out, int N) {
    int lane = threadIdx.x & 31;
    int n = blockIdx.x * 8 + (threadIdx.x >> 5);
    if (n >= N) return;
    int beg = rowstart[n], end = rowstart[n + 1];
    float q = Q[(size_t)n * HS + lane];
    float acc = 0.f, den = 0.f;
    for (int base = beg; base < end; base += 32) {
        int cnt = min(32, end - base);
        int dreg = (base + lane < end) ? sorted_dst[base + lane] : 0;
        for (int j = 0; j < cnt; ++j) {
            int d = __shfl(dreg, j, 32);
            float p = q * K[(size_t)d * HS + lane];
#pragma unroll
            for (int off = 16; off > 0; off >>= 1) p += __shfl_xor(p, off, 32);
            float ex = __expf(p * 0.17677669529663687f);  // 1/sqrt(32)
            den += ex;
            acc += ex * V[(size_t)d * HS + lane];
        }
    }
    out[(size_t)n * HS + lane] = (end > beg) ? acc / den : 0.f;
}

extern "C" void kernel_launch(void* const* d_in, const int* in_sizes, int n_in,
                              void* d_out, int out_size, void* d_ws, size_t ws_size,
                              hipStream_t stream) {
    const float* X  = (const float*)d_in[0];
    const int*   ei = (const int*)d_in[1];
    const float* Wq = (const float*)d_in[2];
    const float* Wk = (const float*)d_in[3];
    const float* Wv = (const float*)d_in[4];

    int N = in_sizes[0] / N_INPUT;
    int E = in_sizes[1] / 2;
    const int* src = ei;
    const int* dst = ei + E;

    // ws layout: Q[N*32] K[N*32] V[N*32] floats; deg[N] rowstart[N+1] cursor[N]
    // sorted_dst[E] ints.  Total ~46 MB.
    float* ws = (float*)d_ws;
    float* Q = ws;
    float* K = Q + (size_t)N * HS;
    float* V = K + (size_t)N * HS;
    int* deg = (int*)(V + (size_t)N * HS);
    int* rowstart = deg + N;
    int* cursor = rowstart + (N + 1);
    int* sorted_dst = cursor + N;
    float* out = (float*)d_out;

    int nb = (N + 255) / 256;
    int ebl = (E + 255) / 256;
    zero_deg_kernel<<<nb, 256, 0, stream>>>(deg, N);
    hist_kernel<<<ebl, 256, 0, stream>>>(src, deg, E);
    scan_kernel<<<1, SCAN_T, 0, stream>>>(deg, rowstart, cursor, N, E);
    scatter_kernel<<<ebl, 256, 0, stream>>>(src, dst, cursor, sorted_dst, E);

    int mtiles = (N + 15) / 16;
    qkv_mfma_kernel<<<(mtiles + 3) / 4, 256, 0, stream>>>(X, Wq, Wk, Wv, Q, K, V, N);

    fused_agg_kernel<<<(N + 7) / 8, 256, 0, stream>>>(rowstart, sorted_dst, Q, K, V, out, N);
}

// Round 6
// 456.596 us; speedup vs baseline: 1.4790x; 1.4790x over previous
//
#include <hip/hip_runtime.h>

#define N_INPUT 256
#define HS 32
#define SB 256   // scan block threads
#define SE 1024  // elems per scan block

typedef __attribute__((ext_vector_type(8))) short bf16x8;
typedef __attribute__((ext_vector_type(4))) float f32x4;

// fp32 -> bf16 bits, round-to-nearest-even
__device__ __forceinline__ unsigned short f2bf(float f) {
    unsigned u = __float_as_uint(f);
    unsigned r = u + 0x7FFFu + ((u >> 16) & 1u);
    return (unsigned short)(r >> 16);
}

// ---------------- CSR build: counting sort of edges by src ----------------

__global__ void zero_deg_kernel(int* __restrict__ deg, int N) {
    int i = blockIdx.x * blockDim.x + threadIdx.x;
    if (i < N) deg[i] = 0;
}

__global__ void hist_kernel(const int* __restrict__ src, int* __restrict__ deg, int E) {
    int e = blockIdx.x * blockDim.x + threadIdx.x;
    if (e < E) atomicAdd(deg + src[e], 1);
}

// 3-kernel device-wide exclusive scan. (R5's single-block scan was 231 us:
// one CU, stride-392B uncoalesced loads, latency-bound at 0.15% occupancy.)
__global__ __launch_bounds__(SB) void block_reduce_kernel(
        const int* __restrict__ deg, int* __restrict__ bsum, int N) {
    __shared__ int s[SB];
    int blk = blockIdx.x, t = threadIdx.x;
    int base = blk * SE;
    int sum = 0;
#pragma unroll
    for (int i = 0; i < SE / SB; ++i) {
        int idx = base + i * SB + t;  // coalesced
        if (idx < N) sum += deg[idx];
    }
    s[t] = sum;
    __syncthreads();
    for (int off = SB / 2; off > 0; off >>= 1) {
        if (t < off) s[t] += s[t + off];
        __syncthreads();
    }
    if (t == 0) bsum[blk] = s[0];
}

__global__ __launch_bounds__(SB) void scan_sums_kernel(
        const int* __restrict__ bsum, int* __restrict__ boff, int nblocks,
        int* __restrict__ rowstart, int N, int E) {
    __shared__ int s[SB];
    int t = threadIdx.x;
    int v = (t < nblocks) ? bsum[t] : 0;
    s[t] = v;
    __syncthreads();
    for (int off = 1; off < SB; off <<= 1) {
        int u = (t >= off) ? s[t - off] : 0;
        __syncthreads();
        s[t] += u;
        __syncthreads();
    }
    if (t < nblocks) boff[t] = s[t] - v;  // exclusive block offset
    if (t == 0) rowstart[N] = E;
}

__global__ __launch_bounds__(SB) void emit_kernel(
        const int* __restrict__ deg, const int* __restrict__ boff,
        int* __restrict__ rowstart, int* __restrict__ cursor, int N) {
    __shared__ int s[SB];
    int blk = blockIdx.x, t = threadIdx.x;
    int base = blk * SE + t * 4;
    int4 d = make_int4(0, 0, 0, 0);
    if (base + 3 < N) {
        d = *(const int4*)(deg + base);
    } else {
        if (base + 0 < N) d.x = deg[base + 0];
        if (base + 1 < N) d.y = deg[base + 1];
        if (base + 2 < N) d.z = deg[base + 2];
    }
    int tsum = d.x + d.y + d.z + d.w;
    s[t] = tsum;
    __syncthreads();
    for (int off = 1; off < SB; off <<= 1) {
        int u = (t >= off) ? s[t - off] : 0;
        __syncthreads();
        s[t] += u;
        __syncthreads();
    }
    int pre = boff[blk] + s[t] - tsum;  // exclusive prefix of this thread's 1st elem
    int4 r;
    r.x = pre;
    r.y = r.x + d.x;
    r.z = r.y + d.y;
    r.w = r.z + d.z;
    if (base + 3 < N) {
        *(int4*)(rowstart + base) = r;
        *(int4*)(cursor + base) = r;
    } else {
        if (base + 0 < N) { rowstart[base + 0] = r.x; cursor[base + 0] = r.x; }
        if (base + 1 < N) { rowstart[base + 1] = r.y; cursor[base + 1] = r.y; }
        if (base + 2 < N) { rowstart[base + 2] = r.z; cursor[base + 2] = r.z; }
    }
}

__global__ void scatter_kernel(const int* __restrict__ src, const int* __restrict__ dst,
                               int* __restrict__ cursor, int* __restrict__ sorted_dst, int E) {
    int e = blockIdx.x * blockDim.x + threadIdx.x;
    if (e < E) {
        int pos = atomicAdd(cursor + src[e], 1);
        sorted_dst[pos] = dst[e];
    }
}

// ---------------- Fused Q/K/V projection (MFMA, unchanged from R4) ----------------
__global__ __launch_bounds__(256) void qkv_mfma_kernel(
        const float* __restrict__ X, const float* __restrict__ Wq,
        const float* __restrict__ Wk, const float* __restrict__ Wv,
        float* __restrict__ Q, float* __restrict__ K, float* __restrict__ V, int N) {
    __shared__ unsigned short sB[6 * 8 * 64 * 8];  // 48 KB, frag-ordered bf16 W

    int tid = threadIdx.x;
    for (int i = 0; i < 12; ++i) {
        int c = tid + i * 256;
        int s = c >> 9;
        int t = (c >> 6) & 7;
        int L = c & 63;
        const float* wm = (s < 2) ? Wq : (s < 4) ? Wk : Wv;
        const float* wsrc = wm + (size_t)(t * 32 + (L >> 4) * 8) * HS + (s & 1) * 16 + (L & 15);
        unsigned e0 = f2bf(wsrc[0 * HS]) | ((unsigned)f2bf(wsrc[1 * HS]) << 16);
        unsigned e1 = f2bf(wsrc[2 * HS]) | ((unsigned)f2bf(wsrc[3 * HS]) << 16);
        unsigned e2 = f2bf(wsrc[4 * HS]) | ((unsigned)f2bf(wsrc[5 * HS]) << 16);
        unsigned e3 = f2bf(wsrc[6 * HS]) | ((unsigned)f2bf(wsrc[7 * HS]) << 16);
        ((uint4*)sB)[c] = make_uint4(e0, e1, e2, e3);
    }
    __syncthreads();

    int wave = tid >> 6;
    int L = tid & 63;
    int quad = L >> 4;
    int lane16 = L & 15;
    int mt = blockIdx.x * 4 + wave;
    if (mt * 16 >= N) return;  // no barriers past this point

    const float* xrow = X + (size_t)(mt * 16 + lane16) * N_INPUT + quad * 8;
    bf16x8 afrag[8];
#pragma unroll
    for (int t = 0; t < 8; ++t) {
        float4 a0 = *(const float4*)(xrow + t * 32);
        float4 a1 = *(const float4*)(xrow + t * 32 + 4);
        bf16x8 f;
        f[0] = (short)f2bf(a0.x); f[1] = (short)f2bf(a0.y);
        f[2] = (short)f2bf(a0.z); f[3] = (short)f2bf(a0.w);
        f[4] = (short)f2bf(a1.x); f[5] = (short)f2bf(a1.y);
        f[6] = (short)f2bf(a1.z); f[7] = (short)f2bf(a1.w);
        afrag[t] = f;
    }

#pragma unroll
    for (int s = 0; s < 6; ++s) {
        f32x4 acc = {0.f, 0.f, 0.f, 0.f};
#pragma unroll
        for (int t = 0; t < 8; ++t) {
            bf16x8 bfrag = *((const bf16x8*)sB + (s * 8 + t) * 64 + L);
            acc = __builtin_amdgcn_mfma_f32_16x16x32_bf16(afrag[t], bfrag, acc, 0, 0, 0);
        }
        float* om = (s < 2) ? Q : (s < 4) ? K : V;
        int col = (s & 1) * 16 + lane16;
#pragma unroll
        for (int r = 0; r < 4; ++r) {
            int row = mt * 16 + quad * 4 + r;
            om[(size_t)row * HS + col] = acc[r];
        }
    }
}

// ---------------- Fused per-node edge pass (unchanged from R5) ----------------
__global__ __launch_bounds__(256) void fused_agg_kernel(
        const int* __restrict__ rowstart, const int* __restrict__ sorted_dst,
        const float* __restrict__ Q, const float* __restrict__ K,
        const float* __restrict__ V, float* __restrict__ out, int N) {
    int lane = threadIdx.x & 31;
    int n = blockIdx.x * 8 + (threadIdx.x >> 5);
    if (n >= N) return;
    int beg = rowstart[n], end = rowstart[n + 1];
    float q = Q[(size_t)n * HS + lane];
    float acc = 0.f, den = 0.f;
    for (int base = beg; base < end; base += 32) {
        int cnt = min(32, end - base);
        int dreg = (base + lane < end) ? sorted_dst[base + lane] : 0;
        for (int j = 0; j < cnt; ++j) {
            int d = __shfl(dreg, j, 32);
            float p = q * K[(size_t)d * HS + lane];
#pragma unroll
            for (int off = 16; off > 0; off >>= 1) p += __shfl_xor(p, off, 32);
            float ex = __expf(p * 0.17677669529663687f);  // 1/sqrt(32)
            den += ex;
            acc += ex * V[(size_t)d * HS + lane];
        }
    }
    out[(size_t)n * HS + lane] = (end > beg) ? acc / den : 0.f;
}

extern "C" void kernel_launch(void* const* d_in, const int* in_sizes, int n_in,
                              void* d_out, int out_size, void* d_ws, size_t ws_size,
                              hipStream_t stream) {
    const float* X  = (const float*)d_in[0];
    const int*   ei = (const int*)d_in[1];
    const float* Wq = (const float*)d_in[2];
    const float* Wk = (const float*)d_in[3];
    const float* Wv = (const float*)d_in[4];

    int N = in_sizes[0] / N_INPUT;
    int E = in_sizes[1] / 2;
    const int* src = ei;
    const int* dst = ei + E;

    // ws layout: Q,K,V [N*32] floats; deg[N], rowstart[N+4] (pad for int4-aligned
    // cursor), cursor[N], bsum[256], boff[256], sorted_dst[E] ints.
    float* ws = (float*)d_ws;
    float* Q = ws;
    float* K = Q + (size_t)N * HS;
    float* V = K + (size_t)N * HS;
    int* deg = (int*)(V + (size_t)N * HS);
    int* rowstart = deg + N;
    int* cursor = rowstart + N + 4;
    int* bsum = cursor + N;
    int* boff = bsum + 256;
    int* sorted_dst = boff + 256;
    float* out = (float*)d_out;

    int nb = (N + 255) / 256;
    int ebl = (E + 255) / 256;
    int sblocks = (N + SE - 1) / SE;  // 98
    zero_deg_kernel<<<nb, 256, 0, stream>>>(deg, N);
    hist_kernel<<<ebl, 256, 0, stream>>>(src, deg, E);
    block_reduce_kernel<<<sblocks, SB, 0, stream>>>(deg, bsum, N);
    scan_sums_kernel<<<1, SB, 0, stream>>>(bsum, boff, sblocks, rowstart, N, E);
    emit_kernel<<<sblocks, SB, 0, stream>>>(deg, boff, rowstart, cursor, N);
    scatter_kernel<<<ebl, 256, 0, stream>>>(src, dst, cursor, sorted_dst, E);

    int mtiles = (N + 15) / 16;
    qkv_mfma_kernel<<<(mtiles + 3) / 4, 256, 0, stream>>>(X, Wq, Wk, Wv, Q, K, V, N);

    fused_agg_kernel<<<(N + 7) / 8, 256, 0, stream>>>(rowstart, sorted_dst, Q, K, V, out, N);
}

// Round 7
// 407.702 us; speedup vs baseline: 1.6564x; 1.1199x over previous
//
#include <hip/hip_runtime.h>

#define N_INPUT 256
#define HS 32
#define SB 256   // scan block threads
#define SE 1024  // elems per scan block

typedef __attribute__((ext_vector_type(8))) short bf16x8;
typedef __attribute__((ext_vector_type(4))) float f32x4;

// fp32 -> bf16 bits, round-to-nearest-even
__device__ __forceinline__ unsigned short f2bf(float f) {
    unsigned u = __float_as_uint(f);
    unsigned r = u + 0x7FFFu + ((u >> 16) & 1u);
    return (unsigned short)(r >> 16);
}

// ---------------- CSR build: counting sort of edges by src ----------------

__global__ void zero_deg_kernel(int* __restrict__ deg, int N) {
    int i = blockIdx.x * blockDim.x + threadIdx.x;
    if (i < N) deg[i] = 0;
}

__global__ void hist_kernel(const int* __restrict__ src, int* __restrict__ deg, int E) {
    int e = blockIdx.x * blockDim.x + threadIdx.x;
    if (e < E) atomicAdd(deg + src[e], 1);
}

// 3-kernel device-wide exclusive scan. (R5's single-block scan was 231 us:
// one CU, stride-392B uncoalesced loads, latency-bound at 0.15% occupancy.)
__global__ __launch_bounds__(SB) void block_reduce_kernel(
        const int* __restrict__ deg, int* __restrict__ bsum, int N) {
    __shared__ int s[SB];
    int blk = blockIdx.x, t = threadIdx.x;
    int base = blk * SE;
    int sum = 0;
#pragma unroll
    for (int i = 0; i < SE / SB; ++i) {
        int idx = base + i * SB + t;  // coalesced
        if (idx < N) sum += deg[idx];
    }
    s[t] = sum;
    __syncthreads();
    for (int off = SB / 2; off > 0; off >>= 1) {
        if (t < off) s[t] += s[t + off];
        __syncthreads();
    }
    if (t == 0) bsum[blk] = s[0];
}

__global__ __launch_bounds__(SB) void scan_sums_kernel(
        const int* __restrict__ bsum, int* __restrict__ boff, int nblocks,
        int* __restrict__ rowstart, int N, int E) {
    __shared__ int s[SB];
    int t = threadIdx.x;
    int v = (t < nblocks) ? bsum[t] : 0;
    s[t] = v;
    __syncthreads();
    for (int off = 1; off < SB; off <<= 1) {
        int u = (t >= off) ? s[t - off] : 0;
        __syncthreads();
        s[t] += u;
        __syncthreads();
    }
    if (t < nblocks) boff[t] = s[t] - v;  // exclusive block offset
    if (t == 0) rowstart[N] = E;
}

__global__ __launch_bounds__(SB) void emit_kernel(
        const int* __restrict__ deg, const int* __restrict__ boff,
        int* __restrict__ rowstart, int* __restrict__ cursor, int N) {
    __shared__ int s[SB];
    int blk = blockIdx.x, t = threadIdx.x;
    int base = blk * SE + t * 4;
    int4 d = make_int4(0, 0, 0, 0);
    if (base + 3 < N) {
        d = *(const int4*)(deg + base);
    } else {
        if (base + 0 < N) d.x = deg[base + 0];
        if (base + 1 < N) d.y = deg[base + 1];
        if (base + 2 < N) d.z = deg[base + 2];
    }
    int tsum = d.x + d.y + d.z + d.w;
    s[t] = tsum;
    __syncthreads();
    for (int off = 1; off < SB; off <<= 1) {
        int u = (t >= off) ? s[t - off] : 0;
        __syncthreads();
        s[t] += u;
        __syncthreads();
    }
    int pre = boff[blk] + s[t] - tsum;  // exclusive prefix of this thread's 1st elem
    int4 r;
    r.x = pre;
    r.y = r.x + d.x;
    r.z = r.y + d.y;
    r.w = r.z + d.z;
    if (base + 3 < N) {
        *(int4*)(rowstart + base) = r;
        *(int4*)(cursor + base) = r;
    } else {
        if (base + 0 < N) { rowstart[base + 0] = r.x; cursor[base + 0] = r.x; }
        if (base + 1 < N) { rowstart[base + 1] = r.y; cursor[base + 1] = r.y; }
        if (base + 2 < N) { rowstart[base + 2] = r.z; cursor[base + 2] = r.z; }
    }
}

// XCD-partitioned scatter. (R6's flat scatter: WRITE_SIZE 105 MB for a 6.4 MB
// array -- random 4B writes to lines shared by all 8 XCDs drain per-write.
// Here group g = blockIdx&7 (round-robin XCD heuristic) owns node range g,
// so each output region's lines are written by ONE XCD -> L2 accumulates
// full dirty lines. Cost: 8x edge-list re-read, L2/L3-served.)
__global__ __launch_bounds__(256) void scatter_kernel(
        const int* __restrict__ src, const int* __restrict__ dst,
        int* __restrict__ cursor, int* __restrict__ sorted_dst, int E, int N) {
    int g = blockIdx.x & 7;
    int nlo = (int)(((long long)N * g) >> 3);
    int nhi = (int)(((long long)N * (g + 1)) >> 3);
    int gb = blockIdx.x >> 3;
    int stride = (gridDim.x >> 3) * blockDim.x;
    for (int e = gb * blockDim.x + threadIdx.x; e < E; e += stride) {
        int s = src[e];
        int d = dst[e];  // unconditional coalesced read
        if (s >= nlo && s < nhi) {
            int pos = atomicAdd(cursor + s, 1);
            sorted_dst[pos] = d;
        }
    }
}

// ---------------- Fused Q/K/V projection (MFMA, unchanged from R4) ----------------
__global__ __launch_bounds__(256) void qkv_mfma_kernel(
        const float* __restrict__ X, const float* __restrict__ Wq,
        const float* __restrict__ Wk, const float* __restrict__ Wv,
        float* __restrict__ Q, float* __restrict__ K, float* __restrict__ V, int N) {
    __shared__ unsigned short sB[6 * 8 * 64 * 8];  // 48 KB, frag-ordered bf16 W

    int tid = threadIdx.x;
    for (int i = 0; i < 12; ++i) {
        int c = tid + i * 256;
        int s = c >> 9;
        int t = (c >> 6) & 7;
        int L = c & 63;
        const float* wm = (s < 2) ? Wq : (s < 4) ? Wk : Wv;
        const float* wsrc = wm + (size_t)(t * 32 + (L >> 4) * 8) * HS + (s & 1) * 16 + (L & 15);
        unsigned e0 = f2bf(wsrc[0 * HS]) | ((unsigned)f2bf(wsrc[1 * HS]) << 16);
        unsigned e1 = f2bf(wsrc[2 * HS]) | ((unsigned)f2bf(wsrc[3 * HS]) << 16);
        unsigned e2 = f2bf(wsrc[4 * HS]) | ((unsigned)f2bf(wsrc[5 * HS]) << 16);
        unsigned e3 = f2bf(wsrc[6 * HS]) | ((unsigned)f2bf(wsrc[7 * HS]) << 16);
        ((uint4*)sB)[c] = make_uint4(e0, e1, e2, e3);
    }
    __syncthreads();

    int wave = tid >> 6;
    int L = tid & 63;
    int quad = L >> 4;
    int lane16 = L & 15;
    int mt = blockIdx.x * 4 + wave;
    if (mt * 16 >= N) return;  // no barriers past this point

    const float* xrow = X + (size_t)(mt * 16 + lane16) * N_INPUT + quad * 8;
    bf16x8 afrag[8];
#pragma unroll
    for (int t = 0; t < 8; ++t) {
        float4 a0 = *(const float4*)(xrow + t * 32);
        float4 a1 = *(const float4*)(xrow + t * 32 + 4);
        bf16x8 f;
        f[0] = (short)f2bf(a0.x); f[1] = (short)f2bf(a0.y);
        f[2] = (short)f2bf(a0.z); f[3] = (short)f2bf(a0.w);
        f[4] = (short)f2bf(a1.x); f[5] = (short)f2bf(a1.y);
        f[6] = (short)f2bf(a1.z); f[7] = (short)f2bf(a1.w);
        afrag[t] = f;
    }

#pragma unroll
    for (int s = 0; s < 6; ++s) {
        f32x4 acc = {0.f, 0.f, 0.f, 0.f};
#pragma unroll
        for (int t = 0; t < 8; ++t) {
            bf16x8 bfrag = *((const bf16x8*)sB + (s * 8 + t) * 64 + L);
            acc = __builtin_amdgcn_mfma_f32_16x16x32_bf16(afrag[t], bfrag, acc, 0, 0, 0);
        }
        float* om = (s < 2) ? Q : (s < 4) ? K : V;
        int col = (s & 1) * 16 + lane16;
#pragma unroll
        for (int r = 0; r < 4; ++r) {
            int row = mt * 16 + quad * 4 + r;
            om[(size_t)row * HS + col] = acc[r];
        }
    }
}

// ---------------- Fused per-node edge pass (unchanged from R5) ----------------
__global__ __launch_bounds__(256) void fused_agg_kernel(
        const int* __restrict__ rowstart, const int* __restrict__ sorted_dst,
        const float* __restrict__ Q, const float* __restrict__ K,
        const float* __restrict__ V, float* __restrict__ out, int N) {
    int lane = threadIdx.x & 31;
    int n = blockIdx.x * 8 + (threadIdx.x >> 5);
    if (n >= N) return;
    int beg = rowstart[n], end = rowstart[n + 1];
    float q = Q[(size_t)n * HS + lane];
    float acc = 0.f, den = 0.f;
    for (int base = beg; base < end; base += 32) {
        int cnt = min(32, end - base);
        int dreg = (base + lane < end) ? sorted_dst[base + lane] : 0;
        for (int j = 0; j < cnt; ++j) {
            int d = __shfl(dreg, j, 32);
            float p = q * K[(size_t)d * HS + lane];
#pragma unroll
            for (int off = 16; off > 0; off >>= 1) p += __shfl_xor(p, off, 32);
            float ex = __expf(p * 0.17677669529663687f);  // 1/sqrt(32)
            den += ex;
            acc += ex * V[(size_t)d * HS + lane];
        }
    }
    out[(size_t)n * HS + lane] = (end > beg) ? acc / den : 0.f;
}

extern "C" void kernel_launch(void* const* d_in, const int* in_sizes, int n_in,
                              void* d_out, int out_size, void* d_ws, size_t ws_size,
                              hipStream_t stream) {
    const float* X  = (const float*)d_in[0];
    const int*   ei = (const int*)d_in[1];
    const float* Wq = (const float*)d_in[2];
    const float* Wk = (const float*)d_in[3];
    const float* Wv = (const float*)d_in[4];

    int N = in_sizes[0] / N_INPUT;
    int E = in_sizes[1] / 2;
    const int* src = ei;
    const int* dst = ei + E;

    // ws layout: Q,K,V [N*32] floats; deg[N], rowstart[N+4] (pad for int4-aligned
    // cursor), cursor[N], bsum[256], boff[256], sorted_dst[E] ints.
    float* ws = (float*)d_ws;
    float* Q = ws;
    float* K = Q + (size_t)N * HS;
    float* V = K + (size_t)N * HS;
    int* deg = (int*)(V + (size_t)N * HS);
    int* rowstart = deg + N;
    int* cursor = rowstart + N + 4;
    int* bsum = cursor + N;
    int* boff = bsum + 256;
    int* sorted_dst = boff + 256;
    float* out = (float*)d_out;

    int nb = (N + 255) / 256;
    int ebl = (E + 255) / 256;
    int sblocks = (N + SE - 1) / SE;  // 98
    zero_deg_kernel<<<nb, 256, 0, stream>>>(deg, N);
    hist_kernel<<<ebl, 256, 0, stream>>>(src, deg, E);
    block_reduce_kernel<<<sblocks, SB, 0, stream>>>(deg, bsum, N);
    scan_sums_kernel<<<1, SB, 0, stream>>>(bsum, boff, sblocks, rowstart, N, E);
    emit_kernel<<<sblocks, SB, 0, stream>>>(deg, boff, rowstart, cursor, N);
    scatter_kernel<<<2048, 256, 0, stream>>>(src, dst, cursor, sorted_dst, E, N);

    int mtiles = (N + 15) / 16;
    qkv_mfma_kernel<<<(mtiles + 3) / 4, 256, 0, stream>>>(X, Wq, Wk, Wv, Q, K, V, N);

    fused_agg_kernel<<<(N + 7) / 8, 256, 0, stream>>>(rowstart, sorted_dst, Q, K, V, out, N);
}

// Round 8
// 364.022 us; speedup vs baseline: 1.8551x; 1.1200x over previous
//
#include <hip/hip_runtime.h>

#define N_INPUT 256
#define HS 32
#define SB 256   // scan block threads
#define SE 1024  // elems per scan block

typedef __attribute__((ext_vector_type(8))) short bf16x8;
typedef __attribute__((ext_vector_type(4))) float f32x4;
typedef __attribute__((ext_vector_type(4))) unsigned short u16x4;

// fp32 -> bf16 bits, round-to-nearest-even
__device__ __forceinline__ unsigned short f2bf(float f) {
    unsigned u = __float_as_uint(f);
    unsigned r = u + 0x7FFFu + ((u >> 16) & 1u);
    return (unsigned short)(r >> 16);
}
__device__ __forceinline__ float bf2f(unsigned short u) {
    return __uint_as_float((unsigned)u << 16);
}

// ---------------- CSR build: counting sort of edges by src ----------------

__global__ void zero_deg_kernel(int* __restrict__ deg, int N) {
    int i = blockIdx.x * blockDim.x + threadIdx.x;
    if (i < N) deg[i] = 0;
}

__global__ void hist_kernel(const int* __restrict__ src, int* __restrict__ deg, int E) {
    int e = blockIdx.x * blockDim.x + threadIdx.x;
    if (e < E) atomicAdd(deg + src[e], 1);
}

// 3-kernel device-wide exclusive scan. (R5's single-block scan was 231 us:
// one CU, stride-392B uncoalesced loads, latency-bound at 0.15% occupancy.)
__global__ __launch_bounds__(SB) void block_reduce_kernel(
        const int* __restrict__ deg, int* __restrict__ bsum, int N) {
    __shared__ int s[SB];
    int blk = blockIdx.x, t = threadIdx.x;
    int base = blk * SE;
    int sum = 0;
#pragma unroll
    for (int i = 0; i < SE / SB; ++i) {
        int idx = base + i * SB + t;  // coalesced
        if (idx < N) sum += deg[idx];
    }
    s[t] = sum;
    __syncthreads();
    for (int off = SB / 2; off > 0; off >>= 1) {
        if (t < off) s[t] += s[t + off];
        __syncthreads();
    }
    if (t == 0) bsum[blk] = s[0];
}

__global__ __launch_bounds__(SB) void scan_sums_kernel(
        const int* __restrict__ bsum, int* __restrict__ boff, int nblocks,
        int* __restrict__ rowstart, int N, int E) {
    __shared__ int s[SB];
    int t = threadIdx.x;
    int v = (t < nblocks) ? bsum[t] : 0;
    s[t] = v;
    __syncthreads();
    for (int off = 1; off < SB; off <<= 1) {
        int u = (t >= off) ? s[t - off] : 0;
        __syncthreads();
        s[t] += u;
        __syncthreads();
    }
    if (t < nblocks) boff[t] = s[t] - v;  // exclusive block offset
    if (t == 0) rowstart[N] = E;
}

__global__ __launch_bounds__(SB) void emit_kernel(
        const int* __restrict__ deg, const int* __restrict__ boff,
        int* __restrict__ rowstart, int* __restrict__ cursor, int N) {
    __shared__ int s[SB];
    int blk = blockIdx.x, t = threadIdx.x;
    int base = blk * SE + t * 4;
    int4 d = make_int4(0, 0, 0, 0);
    if (base + 3 < N) {
        d = *(const int4*)(deg + base);
    } else {
        if (base + 0 < N) d.x = deg[base + 0];
        if (base + 1 < N) d.y = deg[base + 1];
        if (base + 2 < N) d.z = deg[base + 2];
    }
    int tsum = d.x + d.y + d.z + d.w;
    s[t] = tsum;
    __syncthreads();
    for (int off = 1; off < SB; off <<= 1) {
        int u = (t >= off) ? s[t - off] : 0;
        __syncthreads();
        s[t] += u;
        __syncthreads();
    }
    int pre = boff[blk] + s[t] - tsum;  // exclusive prefix of this thread's 1st elem
    int4 r;
    r.x = pre;
    r.y = r.x + d.x;
    r.z = r.y + d.y;
    r.w = r.z + d.z;
    if (base + 3 < N) {
        *(int4*)(rowstart + base) = r;
        *(int4*)(cursor + base) = r;
    } else {
        if (base + 0 < N) { rowstart[base + 0] = r.x; cursor[base + 0] = r.x; }
        if (base + 1 < N) { rowstart[base + 1] = r.y; cursor[base + 1] = r.y; }
        if (base + 2 < N) { rowstart[base + 2] = r.z; cursor[base + 2] = r.z; }
    }
}

// XCD-partitioned scatter (R7: WRITE 105 -> ~13 MB; group g=blockIdx&7 owns
// node range g so each sorted_dst region is written by one XCD's L2).
__global__ __launch_bounds__(256) void scatter_kernel(
        const int* __restrict__ src, const int* __restrict__ dst,
        int* __restrict__ cursor, int* __restrict__ sorted_dst, int E, int N) {
    int g = blockIdx.x & 7;
    int nlo = (int)(((long long)N * g) >> 3);
    int nhi = (int)(((long long)N * (g + 1)) >> 3);
    int gb = blockIdx.x >> 3;
    int stride = (gridDim.x >> 3) * blockDim.x;
    for (int e = gb * blockDim.x + threadIdx.x; e < E; e += stride) {
        int s = src[e];
        int d = dst[e];  // unconditional coalesced read
        if (s >= nlo && s < nhi) {
            int pos = atomicAdd(cursor + s, 1);
            sorted_dst[pos] = d;
        }
    }
}

// ---------------- Fused Q/K/V projection (MFMA) ----------------
// Q stored fp32; K,V stored bf16 (64 B rows) for the gather pass.
__global__ __launch_bounds__(256) void qkv_mfma_kernel(
        const float* __restrict__ X, const float* __restrict__ Wq,
        const float* __restrict__ Wk, const float* __restrict__ Wv,
        float* __restrict__ Q, unsigned short* __restrict__ Kb,
        unsigned short* __restrict__ Vb, int N) {
    __shared__ unsigned short sB[6 * 8 * 64 * 8];  // 48 KB, frag-ordered bf16 W

    int tid = threadIdx.x;
    for (int i = 0; i < 12; ++i) {
        int c = tid + i * 256;
        int s = c >> 9;
        int t = (c >> 6) & 7;
        int L = c & 63;
        const float* wm = (s < 2) ? Wq : (s < 4) ? Wk : Wv;
        const float* wsrc = wm + (size_t)(t * 32 + (L >> 4) * 8) * HS + (s & 1) * 16 + (L & 15);
        unsigned e0 = f2bf(wsrc[0 * HS]) | ((unsigned)f2bf(wsrc[1 * HS]) << 16);
        unsigned e1 = f2bf(wsrc[2 * HS]) | ((unsigned)f2bf(wsrc[3 * HS]) << 16);
        unsigned e2 = f2bf(wsrc[4 * HS]) | ((unsigned)f2bf(wsrc[5 * HS]) << 16);
        unsigned e3 = f2bf(wsrc[6 * HS]) | ((unsigned)f2bf(wsrc[7 * HS]) << 16);
        ((uint4*)sB)[c] = make_uint4(e0, e1, e2, e3);
    }
    __syncthreads();

    int wave = tid >> 6;
    int L = tid & 63;
    int quad = L >> 4;
    int lane16 = L & 15;
    int mt = blockIdx.x * 4 + wave;
    if (mt * 16 >= N) return;  // no barriers past this point

    const float* xrow = X + (size_t)(mt * 16 + lane16) * N_INPUT + quad * 8;
    bf16x8 afrag[8];
#pragma unroll
    for (int t = 0; t < 8; ++t) {
        float4 a0 = *(const float4*)(xrow + t * 32);
        float4 a1 = *(const float4*)(xrow + t * 32 + 4);
        bf16x8 f;
        f[0] = (short)f2bf(a0.x); f[1] = (short)f2bf(a0.y);
        f[2] = (short)f2bf(a0.z); f[3] = (short)f2bf(a0.w);
        f[4] = (short)f2bf(a1.x); f[5] = (short)f2bf(a1.y);
        f[6] = (short)f2bf(a1.z); f[7] = (short)f2bf(a1.w);
        afrag[t] = f;
    }

#pragma unroll
    for (int s = 0; s < 6; ++s) {
        f32x4 acc = {0.f, 0.f, 0.f, 0.f};
#pragma unroll
        for (int t = 0; t < 8; ++t) {
            bf16x8 bfrag = *((const bf16x8*)sB + (s * 8 + t) * 64 + L);
            acc = __builtin_amdgcn_mfma_f32_16x16x32_bf16(afrag[t], bfrag, acc, 0, 0, 0);
        }
        int col = (s & 1) * 16 + lane16;
#pragma unroll
        for (int r = 0; r < 4; ++r) {
            int row = mt * 16 + quad * 4 + r;
            if (s < 2) Q[(size_t)row * HS + col] = acc[r];
            else if (s < 4) Kb[(size_t)row * HS + col] = f2bf(acc[r]);
            else Vb[(size_t)row * HS + col] = f2bf(acc[r]);
        }
    }
}

// ---------------- Fused per-node edge pass, v2 ----------------
// 32-lane group per node; 4 edge slots x 8 lanes. Per edge: 8B bf16x4 K/V
// gathers (64B/edge vs R7's 256B), dot = 4 FMA + 3 DPP shuffles (xor 1,2,4),
// V into per-lane float4 acc; slot-sum (xor 8,16) once at the end.
// (R7: one edge at a time, 5-step reduce, fp32 gathers -> 90 us, FETCH 182 MB,
// 34 cyc/edge latency-exposed.)
__global__ __launch_bounds__(256) void fused_agg_kernel(
        const int* __restrict__ rowstart, const int* __restrict__ sorted_dst,
        const float* __restrict__ Q, const unsigned short* __restrict__ Kb,
        const unsigned short* __restrict__ Vb, float* __restrict__ out, int N) {
    int lane = threadIdx.x & 31;
    int n = blockIdx.x * 8 + (threadIdx.x >> 5);
    if (n >= N) return;
    int slot = lane >> 3;  // edge slot 0..3
    int sub = lane & 7;    // lane within slot
    int beg = rowstart[n], end = rowstart[n + 1];
    float4 qf = *(const float4*)(Q + (size_t)n * HS + sub * 4);
    float4 acc = make_float4(0.f, 0.f, 0.f, 0.f);
    float den = 0.f;

    for (int base = beg; base < end; base += 32) {
        int dreg = (base + lane < end) ? sorted_dst[base + lane] : 0;
        int cnt = min(32, end - base);
        for (int j = 0; j < cnt; j += 4) {
            int eidx = j + slot;
            int d = __shfl(dreg, eidx, 32);
            bool valid = (base + eidx) < end;
            u16x4 k4 = *(const u16x4*)(Kb + (size_t)d * HS + sub * 4);
            float p = qf.x * bf2f(k4[0]) + qf.y * bf2f(k4[1]) +
                      qf.z * bf2f(k4[2]) + qf.w * bf2f(k4[3]);
            p += __shfl_xor(p, 1, 32);
            p += __shfl_xor(p, 2, 32);
            p += __shfl_xor(p, 4, 32);
            float ex = valid ? __expf(p * 0.17677669529663687f) : 0.f;  // 1/sqrt(32)
            den += ex;
            u16x4 v4 = *(const u16x4*)(Vb + (size_t)d * HS + sub * 4);
            acc.x += ex * bf2f(v4[0]);
            acc.y += ex * bf2f(v4[1]);
            acc.z += ex * bf2f(v4[2]);
            acc.w += ex * bf2f(v4[3]);
        }
    }
    // sum the 4 edge slots (xor over slot bits 3,4)
#pragma unroll
    for (int off = 8; off <= 16; off <<= 1) {
        acc.x += __shfl_xor(acc.x, off, 32);
        acc.y += __shfl_xor(acc.y, off, 32);
        acc.z += __shfl_xor(acc.z, off, 32);
        acc.w += __shfl_xor(acc.w, off, 32);
        den += __shfl_xor(den, off, 32);
    }
    if (lane < 8) {
        float4 o = make_float4(0.f, 0.f, 0.f, 0.f);
        if (end > beg) {
            float rd = 1.f / den;
            o = make_float4(acc.x * rd, acc.y * rd, acc.z * rd, acc.w * rd);
        }
        *(float4*)(out + (size_t)n * HS + lane * 4) = o;
    }
}

extern "C" void kernel_launch(void* const* d_in, const int* in_sizes, int n_in,
                              void* d_out, int out_size, void* d_ws, size_t ws_size,
                              hipStream_t stream) {
    const float* X  = (const float*)d_in[0];
    const int*   ei = (const int*)d_in[1];
    const float* Wq = (const float*)d_in[2];
    const float* Wk = (const float*)d_in[3];
    const float* Wv = (const float*)d_in[4];

    int N = in_sizes[0] / N_INPUT;
    int E = in_sizes[1] / 2;
    const int* src = ei;
    const int* dst = ei + E;

    // ws layout: Q[N*32] fp32; Kb[N*32], Vb[N*32] bf16; deg[N], rowstart[N+4]
    // (pad keeps cursor int4-aligned), cursor[N], bsum[256], boff[256],
    // sorted_dst[E] ints.
    float* ws = (float*)d_ws;
    float* Q = ws;
    unsigned short* Kb = (unsigned short*)(Q + (size_t)N * HS);
    unsigned short* Vb = Kb + (size_t)N * HS;
    int* deg = (int*)(Vb + (size_t)N * HS);
    int* rowstart = deg + N;
    int* cursor = rowstart + N + 4;
    int* bsum = cursor + N;
    int* boff = bsum + 256;
    int* sorted_dst = boff + 256;
    float* out = (float*)d_out;

    int nb = (N + 255) / 256;
    int ebl = (E + 255) / 256;
    int sblocks = (N + SE - 1) / SE;  // 98
    zero_deg_kernel<<<nb, 256, 0, stream>>>(deg, N);
    hist_kernel<<<ebl, 256, 0, stream>>>(src, deg, E);
    block_reduce_kernel<<<sblocks, SB, 0, stream>>>(deg, bsum, N);
    scan_sums_kernel<<<1, SB, 0, stream>>>(bsum, boff, sblocks, rowstart, N, E);
    emit_kernel<<<sblocks, SB, 0, stream>>>(deg, boff, rowstart, cursor, N);
    scatter_kernel<<<2048, 256, 0, stream>>>(src, dst, cursor, sorted_dst, E, N);

    int mtiles = (N + 15) / 16;
    qkv_mfma_kernel<<<(mtiles + 3) / 4, 256, 0, stream>>>(X, Wq, Wk, Wv, Q, Kb, Vb, N);

    fused_agg_kernel<<<(N + 7) / 8, 256, 0, stream>>>(rowstart, sorted_dst, Q, Kb, Vb, out, N);
}